// Round 12
// baseline (381.487 us; speedup 1.0000x reference)
//
#include <hip/hip_runtime.h>

#define B_ 2
#define L_ 2048
#define D_ 512
#define H_ 8
#define S_ 2048

typedef __attribute__((ext_vector_type(8))) short short8;
typedef __attribute__((ext_vector_type(8))) unsigned short ushort8;
typedef __attribute__((ext_vector_type(4))) unsigned short ushort4v;
typedef __attribute__((ext_vector_type(4))) float f32x4;
typedef __attribute__((ext_vector_type(16))) float f32x16;
typedef __attribute__((ext_vector_type(4))) float float4v;
typedef __attribute__((ext_vector_type(8))) _Float16 half8;
typedef __attribute__((ext_vector_type(4))) _Float16 half4;

__device__ __forceinline__ unsigned short f2bf(float f) {
    unsigned u = __float_as_uint(f);
    u += 0x7FFF + ((u >> 16) & 1);   // RTNE
    return (unsigned short)(u >> 16);
}
__device__ __forceinline__ float bf2f(unsigned short s) {
    return __uint_as_float(((unsigned)s) << 16);
}
__device__ __forceinline__ unsigned char f2fp8(float f) {
    return (unsigned char)(__builtin_amdgcn_cvt_pk_fp8_f32(f, f, 0, false) & 0xff);
}
__device__ __forceinline__ long pack8fp8(const float* v) {
    int lo = __builtin_amdgcn_cvt_pk_fp8_f32(v[0], v[1], 0, false);
    lo = __builtin_amdgcn_cvt_pk_fp8_f32(v[2], v[3], lo, true);
    int hi = __builtin_amdgcn_cvt_pk_fp8_f32(v[4], v[5], 0, false);
    hi = __builtin_amdgcn_cvt_pk_fp8_f32(v[6], v[7], hi, true);
    union { int i[2]; long l; } u;
    u.i[0] = lo; u.i[1] = hi;
    return u.l;
}
__device__ __forceinline__ int swap23(int x) {
    return (x & ~12) | ((x & 4) << 1) | ((x & 8) >> 1);
}
// async global->LDS, 16B per lane; LDS arg = WAVE-UNIFORM base (HW adds lane*16); global arg per-lane
__device__ __forceinline__ void async16(void* lds, const void* g) {
    __builtin_amdgcn_global_load_lds(
        (const __attribute__((address_space(1))) void*)(g),
        (__attribute__((address_space(3))) void*)(lds), 16, 0, 0);
}

// ---------------- fused: fp32->bf16 converts + content bias (frag-major f32, log2e/8-scaled) ----------------
__global__ __launch_bounds__(256) void cvt_cb(const float* __restrict__ x,
                                              const float* __restrict__ w0, const float* __restrict__ w1,
                                              const float* __restrict__ w2, const float* __restrict__ w3,
                                              const float* __restrict__ Wb,
                                              unsigned short* __restrict__ xb,
                                              unsigned short* __restrict__ d0, unsigned short* __restrict__ d1,
                                              unsigned short* __restrict__ d2, unsigned short* __restrict__ d3,
                                              float* __restrict__ cbf) {
    if (blockIdx.x < 3072) {
        int i = blockIdx.x * 256 + threadIdx.x;
        const float* s;
        unsigned short* d;
        int idx;
        if (i < 524288) { s = x; d = xb; idx = i; }
        else {
            int off = i - 524288;
            int wsel = off >> 16; idx = off & 65535;
            s = (wsel == 0) ? w0 : (wsel == 1) ? w1 : (wsel == 2) ? w2 : w3;
            d = (wsel == 0) ? d0 : (wsel == 1) ? d1 : (wsel == 2) ? d2 : d3;
        }
        float4v v = *(const float4v*)(s + (size_t)idx * 4);
        ushort4v o;
        o[0] = f2bf(v[0]); o[1] = f2bf(v[1]); o[2] = f2bf(v[2]); o[3] = f2bf(v[3]);
        *(ushort4v*)(d + (size_t)idx * 4) = o;
    } else {
        const int tid = threadIdx.x, w = tid >> 6, lane = tid & 63;
        const int row = (blockIdx.x - 3072) * 4 + w;
        const int h = lane >> 3, seg = lane & 7;
        const float* xp = x + (size_t)row * 512 + seg * 64;
        const float* wp = Wb + (size_t)h * 512 + seg * 64;
        float acc = 0.f;
        #pragma unroll
        for (int j = 0; j < 16; ++j) {
            float4v xv = *(const float4v*)(xp + j * 4);
            float4v wv = *(const float4v*)(wp + j * 4);
            acc += xv[0] * wv[0] + xv[1] * wv[1] + xv[2] * wv[2] + xv[3] * wv[3];
        }
        acc += __shfl_xor(acc, 1);
        acc += __shfl_xor(acc, 2);
        acc += __shfl_xor(acc, 4);
        if (seg == 0) {
            int b = row >> 11, s = row & 2047;
            int T = s >> 5, off = s & 31;
            int r2 = off & 3, k = off >> 2;
            int u = (k & 1) + ((k >> 2) << 1), hi2 = (k >> 1) & 1;
            int R = 4 * u + r2;
            cbf[((size_t)((b * 8 + h) * 64 + T)) * 32 + hi2 * 16 + R] = acc * 0.125f * 1.44269504f;
        }
    }
}

// ---------------- q,k,v projections: async-DMA staged core (m97 pattern), 1 barrier/kc ----------------
// LDS tiles linear [row 128][chunk 8][16B]; chunk c of row r holds GLOBAL chunk (c ^ (r&7))
// (rule #21: linear dest + pre-swizzled source + swizzled read). Double-buffered: 64 KB.
__global__ __launch_bounds__(256) void gemm_qkv(const unsigned short* __restrict__ xb,
                                                const unsigned short* __restrict__ Wqb,
                                                const unsigned short* __restrict__ Wkb,
                                                const unsigned short* __restrict__ Wvb,
                                                unsigned short* __restrict__ qb,
                                                unsigned char* __restrict__ kpack8,
                                                unsigned short* __restrict__ vfrag) {
    __shared__ char sAB[2][32768];   // [buf][ A 16KB | B 16KB ]
    const int m0 = blockIdx.x * 128, n0 = blockIdx.y * 128, z = blockIdx.z;
    const unsigned short* Bsel = (z == 0) ? Wqb : ((z == 1) ? Wkb : Wvb);
    const int tid = threadIdx.x, w = tid >> 6, lane = tid & 63, quad = lane >> 4, l15 = lane & 15;
    const int wm = (w >> 1) * 64, wn = (w & 1) * 64;
    const char* Ab = (const char*)(xb + (size_t)m0 * 512);
    const char* Bb = (const char*)(Bsel + (size_t)n0 * 512);
    const int srow = tid >> 3;
    const int csw = (tid & 7) ^ (srow & 7);
    const size_t srcOff = (size_t)srow * 1024 + (size_t)csw * 16;   // bytes
    auto stage = [&](int kc, int bi) {
        char* ba = &sAB[bi][0];
        #pragma unroll
        for (int j = 0; j < 4; ++j)
            async16(ba + j * 4096 + w * 1024, Ab + (size_t)j * 32768 + kc * 128 + srcOff);
        #pragma unroll
        for (int j = 0; j < 4; ++j)
            async16(ba + 16384 + j * 4096 + w * 1024, Bb + (size_t)j * 32768 + kc * 128 + srcOff);
    };

    f32x4 c[4][4];
    #pragma unroll
    for (int ii = 0; ii < 4; ++ii)
        #pragma unroll
        for (int jj = 0; jj < 4; ++jj) { f32x4 zv = {0.f, 0.f, 0.f, 0.f}; c[ii][jj] = zv; }

    stage(0, 0);
    for (int kc = 0; kc < 8; ++kc) {
        __syncthreads();
        if (kc < 7) stage(kc + 1, (kc + 1) & 1);
        const char* tA = &sAB[kc & 1][0];
        const char* tB = &sAB[kc & 1][16384];
        #pragma unroll
        for (int ks = 0; ks < 2; ++ks) {
            short8 a[4], b[4];
            #pragma unroll
            for (int ii = 0; ii < 4; ++ii) {
                int row = wm + ii * 16 + l15;
                a[ii] = *(const short8*)(tA + row * 128 + (((ks * 4 + quad) ^ (l15 & 7)) * 16));
            }
            #pragma unroll
            for (int jj = 0; jj < 4; ++jj) {
                int row = wn + jj * 16 + l15;
                b[jj] = *(const short8*)(tB + row * 128 + (((ks * 4 + quad) ^ (l15 & 7)) * 16));
            }
            #pragma unroll
            for (int ii = 0; ii < 4; ++ii)
                #pragma unroll
                for (int jj = 0; jj < 4; ++jj)
                    c[ii][jj] = __builtin_amdgcn_mfma_f32_16x16x32_bf16(a[ii], b[jj], c[ii][jj], 0, 0, 0);
        }
    }

    const int tid2 = threadIdx.x;
    (void)tid2;
    #pragma unroll
    for (int ii = 0; ii < 4; ++ii) {
        const int mb = m0 + wm + ii * 16 + quad * 4;
        const int bb = mb >> 11;
        if (z == 0) {
            #pragma unroll
            for (int jj = 0; jj < 4; ++jj) {
                int ncol = n0 + wn + jj * 16 + l15;
                #pragma unroll
                for (int r = 0; r < 4; ++r)
                    qb[(size_t)(mb + r) * 512 + ncol] = f2bf(c[ii][jj][r]);
            }
        } else if (z == 1) {
            #pragma unroll
            for (int jj = 0; jj < 4; ++jj) {
                int d = n0 + wn + jj * 16 + l15;
                int pair = d >> 5, fh = (d >> 4) & 1, hid = (d >> 3) & 1, jq = d & 7;
                #pragma unroll
                for (int r = 0; r < 4; ++r) {
                    int s = (mb + r) & 2047;
                    int t = s >> 5, rr = swap23(s & 31);
                    kpack8[(((size_t)(bb * 64 + t) * 16 + pair) << 10)
                           + (hid * 32 + rr) * 16 + fh * 8 + jq] = f2fp8(c[ii][jj][r] * 32.f);
                }
            }
        } else {
            const int hh = (n0 + wn) >> 6;
            const int s = mb & 2047;
            #pragma unroll
            for (int jj = 0; jj < 4; ++jj) {
                int dh = jj * 16 + l15;
                ushort4v o;
                o[0] = f2bf(c[ii][jj][0]); o[1] = f2bf(c[ii][jj][1]);
                o[2] = f2bf(c[ii][jj][2]); o[3] = f2bf(c[ii][jj][3]);
                size_t blk = ((size_t)(bb * H_ + hh) * 64 + (s >> 5)) * 4
                           + ((dh >> 5) * 2 + ((s >> 4) & 1));
                *(ushort4v*)(vfrag + blk * 512 + (dh & 31) * 8 + ((s >> 3) & 1) * 256 + (s & 7)) = o;
            }
        }
    }
}

// ---------------- fused merge(x4) + output projection ----------------
// Opart q-major: partial j of (qt,h,b) at Opart + ((base+j)<<13), base = (qt<<6)|(h<<3)|(b<<2).
__global__ __launch_bounds__(256) void gemm_out(const _Float16* __restrict__ Opart,
                                                const float* __restrict__ lpart,
                                                const unsigned short* __restrict__ Wdb,
                                                const float* __restrict__ bd,
                                                float* __restrict__ out) {
    __shared__ short sA[128 * 72];
    __shared__ short sB[128 * 72];
    const int m0 = blockIdx.x * 128, n0 = blockIdx.y * 128;
    const int tid = threadIdx.x, w = tid >> 6, lane = tid & 63, quad = lane >> 4, l15 = lane & 15;
    const int wm = (w >> 1) * 64, wn = (w & 1) * 64;
    f32x4 c[4][4];
    #pragma unroll
    for (int ii = 0; ii < 4; ++ii)
        #pragma unroll
        for (int jj = 0; jj < 4; ++jj) { f32x4 zv = {0.f, 0.f, 0.f, 0.f}; c[ii][jj] = zv; }
    for (int kc = 0; kc < 8; ++kc) {
        __syncthreads();
        #pragma unroll
        for (int j = 0; j < 4; ++j) {
            int i = tid + j * 256;
            int row = i >> 3, seg = i & 7;
            int gq = m0 + row;
            int b = gq >> 11, ql = gq & 2047, qq = ql & 127;
            int base = ((ql >> 7) << 6) | (kc << 3) | (b << 2);
            const _Float16* o0 = Opart + ((size_t)base << 13) + qq * 64 + seg * 8;
            float l = lpart[(size_t)base * 128 + qq] + lpart[(size_t)(base + 1) * 128 + qq]
                    + lpart[(size_t)(base + 2) * 128 + qq] + lpart[(size_t)(base + 3) * 128 + qq];
            float inv = __builtin_amdgcn_rcpf(l);
            half8 v0 = *(const half8*)o0;
            half8 v1 = *(const half8*)(o0 + 8192);
            half8 v2 = *(const half8*)(o0 + 16384);
            half8 v3 = *(const half8*)(o0 + 24576);
            ushort8 ov;
            #pragma unroll
            for (int e = 0; e < 8; ++e)
                ov[e] = f2bf(((float)v0[e] + (float)v1[e] + (float)v2[e] + (float)v3[e]) * inv);
            *(ushort8*)&sA[row * 72 + seg * 8] = ov;
            *(ushort8*)&sB[row * 72 + seg * 8] =
                *(const ushort8*)(Wdb + (size_t)(n0 + row) * 512 + kc * 64 + seg * 8);
        }
        __syncthreads();
        #pragma unroll
        for (int ks = 0; ks < 2; ++ks) {
            short8 a[4], b2[4];
            #pragma unroll
            for (int ii = 0; ii < 4; ++ii)
                a[ii] = *(const short8*)&sA[(wm + ii * 16 + l15) * 72 + ks * 32 + quad * 8];
            #pragma unroll
            for (int jj = 0; jj < 4; ++jj)
                b2[jj] = *(const short8*)&sB[(wn + jj * 16 + l15) * 72 + ks * 32 + quad * 8];
            #pragma unroll
            for (int ii = 0; ii < 4; ++ii)
                #pragma unroll
                for (int jj = 0; jj < 4; ++jj)
                    c[ii][jj] = __builtin_amdgcn_mfma_f32_16x16x32_bf16(a[ii], b2[jj], c[ii][jj], 0, 0, 0);
        }
    }
    #pragma unroll
    for (int ii = 0; ii < 4; ++ii) {
        const int mb = m0 + wm + ii * 16 + quad * 4;
        #pragma unroll
        for (int jj = 0; jj < 4; ++jj) {
            int ncol = n0 + wn + jj * 16 + l15;
            float bias = bd[ncol];
            #pragma unroll
            for (int r = 0; r < 4; ++r)
                out[(size_t)(mb + r) * 512 + ncol] = c[ii][jj][r] + bias;
        }
    }
}

// ---------------- flash attention v20: split-S x4 (16 tiles/block), 3 blocks/CU resident ----------------
// v19 core verbatim; only the S-range decomposition changes. bid = half(2b) | b<<2 | h<<3 | qt<<6;
// grid 1024. LDS 48KB -> 3 blocks/CU (was grid-limited to 2). Ring/parity re-verified:
// tile t -> buf t%3, phase 15 in buf0, bank parity = t&1 (15 odd ≡ old 31 odd).
__global__ __launch_bounds__(256, 3) void flash_attn(const unsigned short* __restrict__ qb,
                                                     const unsigned char* __restrict__ kpack8,
                                                     const unsigned short* __restrict__ vfrag,
                                                     const float* __restrict__ cbf_all,
                                                     const float* __restrict__ mixing,
                                                     _Float16* __restrict__ Opart,
                                                     float* __restrict__ lpart) {
    __shared__ char sK[3][16384];
    const int bid = blockIdx.x;
    const int half = bid & 3, b = (bid >> 2) & 1, h = (bid >> 3) & 7, qt = bid >> 6;
    const int tid = threadIdx.x, w = tid >> 6, lane = tid & 63;
    const int l31 = lane & 31, hi = lane >> 5;
    const int q0 = qt * 128 + w * 32;
    const unsigned short* vfb = vfrag + ((size_t)(b * H_ + h) * 64 + half * 16) * 2048;
    const float* cbfb = cbf_all + ((size_t)((b * 8 + h) * 64 + half * 16)) * 32 + hi * 16;
    const float* mixh = mixing + h * D_;
    const float SC = 1.44269504f / 4096.0f;

    long qq[32];
    {
        const unsigned short* qrow = qb + ((size_t)(b * L_) + q0 + l31) * D_ + hi * 8;
        #pragma unroll
        for (int i = 0; i < 32; ++i) {
            ushort8 qv = *(const ushort8*)(qrow + i * 16);
            float4v ma = *(const float4v*)(mixh + i * 16 + hi * 8);
            float4v mb = *(const float4v*)(mixh + i * 16 + hi * 8 + 4);
            float v[8];
            v[0] = bf2f(qv[0]) * ma[0] * 16.f;
            v[1] = bf2f(qv[1]) * ma[1] * 16.f;
            v[2] = bf2f(qv[2]) * ma[2] * 16.f;
            v[3] = bf2f(qv[3]) * ma[3] * 16.f;
            v[4] = bf2f(qv[4]) * mb[0] * 16.f;
            v[5] = bf2f(qv[5]) * mb[1] * 16.f;
            v[6] = bf2f(qv[6]) * mb[2] * 16.f;
            v[7] = bf2f(qv[7]) * mb[3] * 16.f;
            qq[i] = pack8fp8(v);
        }
    }
    asm volatile("s_waitcnt vmcnt(0)" ::: "memory");

    f32x16 acco0, acco1;
    #pragma unroll
    for (int i = 0; i < 16; ++i) { acco0[i] = 0.f; acco1[i] = 0.f; }
    float lsum = 0.f;
    f32x16 aA0, aB0, aA1, aB1;
    short8 av00, av01, av10, av11;
    float4v cbf0, cbf1, cbf2, cbf3;

    auto stageK2 = [&](int t, int bi) {
        const char* src = (const char*)kpack8 + (((size_t)(b * 64 + half * 16 + t)) << 14);
        char* dst = &sK[bi][0];
        #pragma unroll
        for (int ii = 0; ii < 4; ++ii)
            async16(dst + w * 1024 + ii * 4096, src + w * 1024 + ii * 4096 + (size_t)lane * 16);
    };
    auto ldV = [&](int t) {
        const unsigned short* vp = vfb + (size_t)t * 2048 + lane * 8;
        av00 = *(const short8*)(vp);
        av01 = *(const short8*)(vp + 512);
        av10 = *(const short8*)(vp + 1024);
        av11 = *(const short8*)(vp + 1536);
        asm volatile("" ::: "memory");
    };
    auto ldCB = [&](int t) {
        const float* cp = cbfb + t * 32;
        cbf0 = *(const float4v*)(cp);
        cbf1 = *(const float4v*)(cp + 4);
        cbf2 = *(const float4v*)(cp + 8);
        cbf3 = *(const float4v*)(cp + 12);
        asm volatile("" ::: "memory");
    };
    auto cbfv = [&](int R) -> float {
        return (R < 4) ? cbf0[R & 3] : (R < 8) ? cbf1[R & 3] : (R < 12) ? cbf2[R & 3] : cbf3[R & 3];
    };
    auto pack_pv = [&](const float* pex) {
        union { unsigned int u[4]; short8 s8; } P0, P1;
        #pragma unroll
        for (int j = 0; j < 4; ++j) {
            P0.u[j] = __builtin_amdgcn_perm(__float_as_uint(pex[2 * j + 1]) + 0x8000u,
                                            __float_as_uint(pex[2 * j]) + 0x8000u, 0x07060302u);
            P1.u[j] = __builtin_amdgcn_perm(__float_as_uint(pex[8 + 2 * j + 1]) + 0x8000u,
                                            __float_as_uint(pex[8 + 2 * j]) + 0x8000u, 0x07060302u);
        }
        acco0 = __builtin_amdgcn_mfma_f32_32x32x16_bf16(av00, P0.s8, acco0, 0, 0, 0);
        acco0 = __builtin_amdgcn_mfma_f32_32x32x16_bf16(av01, P1.s8, acco0, 0, 0, 0);
        acco1 = __builtin_amdgcn_mfma_f32_32x32x16_bf16(av10, P0.s8, acco1, 0, 0, 0);
        acco1 = __builtin_amdgcn_mfma_f32_32x32x16_bf16(av11, P1.s8, acco1, 0, 0, 0);
    };
    auto tile_fused = [&](const char* buf, int T, f32x16& CA, f32x16& CB,
                          const f32x16& PA, const f32x16& PB) {
        __builtin_amdgcn_s_setprio(1);
        float pex[16];
        float lsA = 0.f, lsB = 0.f;
        #pragma unroll
        for (int fp = 0; fp < 16; ++fp) {
            const long* ap = (const long*)&buf[fp * 1024 + lane * 16];
            long a0 = ap[0], a1 = ap[1];
            CA = __builtin_amdgcn_mfma_f32_32x32x16_fp8_fp8(a0, qq[2 * fp], CA, 0, 0, 0);
            CB = __builtin_amdgcn_mfma_f32_32x32x16_fp8_fp8(a1, qq[2 * fp + 1], CB, 0, 0, 0);
            if (fp < 8) {
                float x0 = fmaf(PA[2 * fp] + PB[2 * fp], SC, cbfv(2 * fp));
                float x1 = fmaf(PA[2 * fp + 1] + PB[2 * fp + 1], SC, cbfv(2 * fp + 1));
                float e0, e1;
                asm("v_exp_f32 %0, %1" : "=v"(e0) : "v"(x0));
                asm("v_exp_f32 %0, %1" : "=v"(e1) : "v"(x1));
                pex[2 * fp] = e0; pex[2 * fp + 1] = e1;
                lsA += e0; lsB += e1;
            }
            if (fp == 8) { lsum += lsA + lsB; pack_pv(pex); }
            if (fp == 9)  ldV(T);
            if (fp == 10) ldCB(T);
        }
        __builtin_amdgcn_s_setprio(0);
    };
    auto tile_plain = [&](const char* buf, int T, f32x16& CA, f32x16& CB) {
        __builtin_amdgcn_s_setprio(1);
        #pragma unroll
        for (int fp = 0; fp < 16; ++fp) {
            const long* ap = (const long*)&buf[fp * 1024 + lane * 16];
            long a0 = ap[0], a1 = ap[1];
            CA = __builtin_amdgcn_mfma_f32_32x32x16_fp8_fp8(a0, qq[2 * fp], CA, 0, 0, 0);
            CB = __builtin_amdgcn_mfma_f32_32x32x16_fp8_fp8(a1, qq[2 * fp + 1], CB, 0, 0, 0);
            if (fp == 9)  ldV(T);
            if (fp == 10) ldCB(T);
        }
        __builtin_amdgcn_s_setprio(0);
    };
    auto sm_pv = [&](const f32x16& PA, const f32x16& PB) {
        float pex[16];
        float lsA = 0.f, lsB = 0.f;
        #pragma unroll
        for (int R = 0; R < 16; R += 2) {
            float x0 = fmaf(PA[R] + PB[R], SC, cbfv(R));
            float x1 = fmaf(PA[R + 1] + PB[R + 1], SC, cbfv(R + 1));
            float e0, e1;
            asm("v_exp_f32 %0, %1" : "=v"(e0) : "v"(x0));
            asm("v_exp_f32 %0, %1" : "=v"(e1) : "v"(x1));
            pex[R] = e0; pex[R + 1] = e1;
            lsA += e0; lsB += e1;
        }
        lsum += lsA + lsB;
        pack_pv(pex);
    };
    auto zero16 = [](f32x16& v) {
        #pragma unroll
        for (int i = 0; i < 16; ++i) v[i] = 0.f;
    };

    // ---- prologue: 2 K-tiles in flight ----
    stageK2(0, 0); stageK2(1, 1);

    // ---- phase 0 (bank0, buf0) ----
    zero16(aA0); zero16(aB0);
    asm volatile("s_waitcnt vmcnt(4)" ::: "memory");
    __builtin_amdgcn_s_barrier();
    tile_plain(&sK[0][0], 0, aA0, aB0);
    stageK2(2, 2);

    // ---- phases 1..14 (ring: tile t -> buf t%3; stage t+2 -> buf (t+2)%3) ----
    int cur = 1;
    for (int t = 1; t <= 14; t += 2) {
        zero16(aA1); zero16(aB1);
        asm volatile("s_waitcnt vmcnt(4)" ::: "memory");
        __builtin_amdgcn_s_barrier();
        tile_fused(&sK[cur][0], t, aA1, aB1, aA0, aB0);
        if (t + 2 <= 15) stageK2(t + 2, (cur + 2 >= 3) ? cur - 1 : cur + 2);
        cur = (cur == 2) ? 0 : cur + 1;

        zero16(aA0); zero16(aB0);
        asm volatile("s_waitcnt vmcnt(4)" ::: "memory");
        __builtin_amdgcn_s_barrier();
        tile_fused(&sK[cur][0], t + 1, aA0, aB0, aA1, aB1);
        if (t + 3 <= 15) stageK2(t + 3, (cur + 2 >= 3) ? cur - 1 : cur + 2);
        cur = (cur == 2) ? 0 : cur + 1;
    }

    // ---- phase 15 (bank1, buf0; deferred softmax of 14 in bank0) ----
    {
        zero16(aA1); zero16(aB1);
        asm volatile("s_waitcnt vmcnt(0)" ::: "memory");
        __builtin_amdgcn_s_barrier();
        tile_fused(&sK[cur][0], 15, aA1, aB1, aA0, aB0);
        asm volatile("s_waitcnt vmcnt(0)" ::: "memory");
        sm_pv(aA1, aB1);
    }

    // ---- epilogue: lsum; O^T -> q-major via sO = sK[0] (free after the phase-15 barrier) ----
    lsum += __shfl_xor(lsum, 32);
    if (hi == 0) lpart[(size_t)bid * 128 + w * 32 + l31] = lsum;
    {
        _Float16* sO = (_Float16*)&sK[1][0];           // buf1: last read was tile 13 (2 barriers ago)
        const int q = w * 32 + l31;
        #pragma unroll
        for (int u = 0; u < 4; ++u) {
            half4 v0, v1;
            v0[0] = (_Float16)acco0[4 * u];     v0[1] = (_Float16)acco0[4 * u + 1];
            v0[2] = (_Float16)acco0[4 * u + 2]; v0[3] = (_Float16)acco0[4 * u + 3];
            v1[0] = (_Float16)acco1[4 * u];     v1[1] = (_Float16)acco1[4 * u + 1];
            v1[2] = (_Float16)acco1[4 * u + 2]; v1[3] = (_Float16)acco1[4 * u + 3];
            *(half4*)&sO[q * 72 + u * 8 + 4 * hi]      = v0;   // dh = 8u + 4hi + 0..3
            *(half4*)&sO[q * 72 + 32 + u * 8 + 4 * hi] = v1;
        }
        const int qd = tid >> 1, hf = tid & 1;
        _Float16* dst = Opart + ((size_t)bid << 13) + qd * 64 + hf * 32;
        const _Float16* srcp = sO + qd * 72 + hf * 32;
        #pragma unroll
        for (int k = 0; k < 4; ++k)
            *(half8*)(dst + k * 8) = *(const half8*)(srcp + k * 8);
    }
}

extern "C" void kernel_launch(void* const* d_in, const int* in_sizes, int n_in,
                              void* d_out, int out_size, void* d_ws, size_t ws_size,
                              hipStream_t stream) {
    (void)in_sizes; (void)n_in; (void)out_size; (void)ws_size;
    const float* x      = (const float*)d_in[0];
    const float* Wq     = (const float*)d_in[1];
    const float* Wk     = (const float*)d_in[2];
    const float* Wv     = (const float*)d_in[3];
    const float* Wb     = (const float*)d_in[4];
    const float* mixing = (const float*)d_in[5];
    const float* Wd     = (const float*)d_in[6];
    const float* bd     = (const float*)d_in[7];
    float* out = (float*)d_out;

    char* ws = (char*)d_ws;
    const size_t MiB = 1048576;
    const size_t KiB = 1024;
    // Aliased zone [0,16MiB): cvt_cb writes xb/Wq/Wk/Wv here; gemm_qkv consumes them; flash then
    // overwrites the zone with Opart (stream-serialized, safe across graph replays).
    _Float16* Opart        = (_Float16*)(ws);                        // [0,16) MiB, q-major x4 split
    unsigned short* xb     = (unsigned short*)(ws);                  // [0,4)
    unsigned short* Wqb    = (unsigned short*)(ws + 4 * MiB);        // [4,4.5)
    unsigned short* Wkb    = (unsigned short*)(ws + 4 * MiB + 512 * KiB);
    unsigned short* Wvb    = (unsigned short*)(ws + 5 * MiB);        // [5,5.5)
    // Non-aliased:
    unsigned short* qb     = (unsigned short*)(ws + 16 * MiB);       // [16,20)
    unsigned char*  kpack8 = (unsigned char*)(ws + 20 * MiB);        // [20,22)
    unsigned short* vfrag  = (unsigned short*)(ws + 22 * MiB);       // [22,26)
    unsigned short* Wdb    = (unsigned short*)(ws + 26 * MiB);       // [26,26.5) — read by gemm_out
    float* cbuf            = (float*)(ws + 26 * MiB + 512 * KiB);    // 128 KB
    float* lpart           = (float*)(ws + 27 * MiB);                // 512 KB; total 27.5 MiB

    cvt_cb<<<4096, 256, 0, stream>>>(x, Wq, Wk, Wv, Wd, Wb, xb, Wqb, Wkb, Wvb, Wdb, cbuf);
    gemm_qkv<<<dim3(32, 4, 3), 256, 0, stream>>>(xb, Wqb, Wkb, Wvb, qb, kpack8, vfrag);
    flash_attn<<<1024, 256, 0, stream>>>(qb, kpack8, vfrag, cbuf, mixing, Opart, lpart);
    gemm_out<<<dim3(32, 4), 256, 0, stream>>>(Opart, lpart, Wdb, bd, out);
}

// Round 13
// 192.180 us; speedup vs baseline: 1.9850x; 1.9850x over previous
//
#include <hip/hip_runtime.h>

#define B_ 2
#define L_ 2048
#define D_ 512
#define H_ 8
#define S_ 2048

typedef __attribute__((ext_vector_type(8))) short short8;
typedef __attribute__((ext_vector_type(8))) unsigned short ushort8;
typedef __attribute__((ext_vector_type(4))) unsigned short ushort4v;
typedef __attribute__((ext_vector_type(4))) float f32x4;
typedef __attribute__((ext_vector_type(16))) float f32x16;
typedef __attribute__((ext_vector_type(4))) float float4v;
typedef __attribute__((ext_vector_type(8))) _Float16 half8;
typedef __attribute__((ext_vector_type(4))) _Float16 half4;

__device__ __forceinline__ unsigned short f2bf(float f) {
    unsigned u = __float_as_uint(f);
    u += 0x7FFF + ((u >> 16) & 1);   // RTNE
    return (unsigned short)(u >> 16);
}
__device__ __forceinline__ float bf2f(unsigned short s) {
    return __uint_as_float(((unsigned)s) << 16);
}
__device__ __forceinline__ unsigned char f2fp8(float f) {
    return (unsigned char)(__builtin_amdgcn_cvt_pk_fp8_f32(f, f, 0, false) & 0xff);
}
__device__ __forceinline__ long pack8fp8(const float* v) {
    int lo = __builtin_amdgcn_cvt_pk_fp8_f32(v[0], v[1], 0, false);
    lo = __builtin_amdgcn_cvt_pk_fp8_f32(v[2], v[3], lo, true);
    int hi = __builtin_amdgcn_cvt_pk_fp8_f32(v[4], v[5], 0, false);
    hi = __builtin_amdgcn_cvt_pk_fp8_f32(v[6], v[7], hi, true);
    union { int i[2]; long l; } u;
    u.i[0] = lo; u.i[1] = hi;
    return u.l;
}
__device__ __forceinline__ int swap23(int x) {
    return (x & ~12) | ((x & 4) << 1) | ((x & 8) >> 1);
}
// async global->LDS, 16B per lane; LDS arg = WAVE-UNIFORM base (HW adds lane*16); global arg per-lane
__device__ __forceinline__ void async16(void* lds, const void* g) {
    __builtin_amdgcn_global_load_lds(
        (const __attribute__((address_space(1))) void*)(g),
        (__attribute__((address_space(3))) void*)(lds), 16, 0, 0);
}

// ---------------- fused: fp32->bf16 converts + content bias (frag-major f32, log2e/8-scaled) ----------------
__global__ __launch_bounds__(256) void cvt_cb(const float* __restrict__ x,
                                              const float* __restrict__ w0, const float* __restrict__ w1,
                                              const float* __restrict__ w2, const float* __restrict__ w3,
                                              const float* __restrict__ Wb,
                                              unsigned short* __restrict__ xb,
                                              unsigned short* __restrict__ d0, unsigned short* __restrict__ d1,
                                              unsigned short* __restrict__ d2, unsigned short* __restrict__ d3,
                                              float* __restrict__ cbf) {
    if (blockIdx.x < 3072) {
        int i = blockIdx.x * 256 + threadIdx.x;
        const float* s;
        unsigned short* d;
        int idx;
        if (i < 524288) { s = x; d = xb; idx = i; }
        else {
            int off = i - 524288;
            int wsel = off >> 16; idx = off & 65535;
            s = (wsel == 0) ? w0 : (wsel == 1) ? w1 : (wsel == 2) ? w2 : w3;
            d = (wsel == 0) ? d0 : (wsel == 1) ? d1 : (wsel == 2) ? d2 : d3;
        }
        float4v v = *(const float4v*)(s + (size_t)idx * 4);
        ushort4v o;
        o[0] = f2bf(v[0]); o[1] = f2bf(v[1]); o[2] = f2bf(v[2]); o[3] = f2bf(v[3]);
        *(ushort4v*)(d + (size_t)idx * 4) = o;
    } else {
        const int tid = threadIdx.x, w = tid >> 6, lane = tid & 63;
        const int row = (blockIdx.x - 3072) * 4 + w;
        const int h = lane >> 3, seg = lane & 7;
        const float* xp = x + (size_t)row * 512 + seg * 64;
        const float* wp = Wb + (size_t)h * 512 + seg * 64;
        float acc = 0.f;
        #pragma unroll
        for (int j = 0; j < 16; ++j) {
            float4v xv = *(const float4v*)(xp + j * 4);
            float4v wv = *(const float4v*)(wp + j * 4);
            acc += xv[0] * wv[0] + xv[1] * wv[1] + xv[2] * wv[2] + xv[3] * wv[3];
        }
        acc += __shfl_xor(acc, 1);
        acc += __shfl_xor(acc, 2);
        acc += __shfl_xor(acc, 4);
        if (seg == 0) {
            int b = row >> 11, s = row & 2047;
            int T = s >> 5, off = s & 31;
            int r2 = off & 3, k = off >> 2;
            int u = (k & 1) + ((k >> 2) << 1), hi2 = (k >> 1) & 1;
            int R = 4 * u + r2;
            cbf[((size_t)((b * 8 + h) * 64 + T)) * 32 + hi2 * 16 + R] = acc * 0.125f * 1.44269504f;
        }
    }
}

// ---------------- 128x128-tile GEMM core (register-staged; used by gemm_out) ----------------
__device__ __forceinline__ void gemm128_core(const unsigned short* __restrict__ Ap,
                                             const unsigned short* __restrict__ Bp,
                                             short* sA, short* sB, int tid, f32x4 c[4][4]) {
    const int w = tid >> 6, lane = tid & 63, quad = lane >> 4, l15 = lane & 15;
    const int wm = (w >> 1) * 64, wn = (w & 1) * 64;
    for (int kc = 0; kc < 8; ++kc) {
        __syncthreads();
        #pragma unroll
        for (int j = 0; j < 4; ++j) {
            int i = tid + j * 256;
            int row = i >> 3, seg = i & 7;
            *(ushort8*)&sA[row * 72 + seg * 8] = *(const ushort8*)(Ap + (size_t)row * 512 + kc * 64 + seg * 8);
            *(ushort8*)&sB[row * 72 + seg * 8] = *(const ushort8*)(Bp + (size_t)row * 512 + kc * 64 + seg * 8);
        }
        __syncthreads();
        #pragma unroll
        for (int ks = 0; ks < 2; ++ks) {
            short8 a[4], b[4];
            #pragma unroll
            for (int ii = 0; ii < 4; ++ii)
                a[ii] = *(const short8*)&sA[(wm + ii * 16 + l15) * 72 + ks * 32 + quad * 8];
            #pragma unroll
            for (int jj = 0; jj < 4; ++jj)
                b[jj] = *(const short8*)&sB[(wn + jj * 16 + l15) * 72 + ks * 32 + quad * 8];
            #pragma unroll
            for (int ii = 0; ii < 4; ++ii)
                #pragma unroll
                for (int jj = 0; jj < 4; ++jj)
                    c[ii][jj] = __builtin_amdgcn_mfma_f32_16x16x32_bf16(a[ii], b[jj], c[ii][jj], 0, 0, 0);
        }
    }
}

// ---------------- q,k,v projections: async-DMA staged core (m97 pattern), 1 barrier/kc ----------------
// LDS tiles linear [row 128][chunk 8][16B]; chunk c of row r holds GLOBAL chunk (c ^ (r&7))
// (rule #21: linear dest + pre-swizzled source + swizzled read). Double-buffered: 64 KB.
__global__ __launch_bounds__(256) void gemm_qkv(const unsigned short* __restrict__ xb,
                                                const unsigned short* __restrict__ Wqb,
                                                const unsigned short* __restrict__ Wkb,
                                                const unsigned short* __restrict__ Wvb,
                                                unsigned short* __restrict__ qb,
                                                unsigned char* __restrict__ kpack8,
                                                unsigned short* __restrict__ vfrag) {
    __shared__ char sAB[2][32768];   // [buf][ A 16KB | B 16KB ]
    const int m0 = blockIdx.x * 128, n0 = blockIdx.y * 128, z = blockIdx.z;
    const unsigned short* Bsel = (z == 0) ? Wqb : ((z == 1) ? Wkb : Wvb);
    const int tid = threadIdx.x, w = tid >> 6, lane = tid & 63, quad = lane >> 4, l15 = lane & 15;
    const int wm = (w >> 1) * 64, wn = (w & 1) * 64;
    const char* Ab = (const char*)(xb + (size_t)m0 * 512);
    const char* Bb = (const char*)(Bsel + (size_t)n0 * 512);
    // staging: slot(j) = j*256 + tid -> row = j*32 + (tid>>3), c = tid&7; source chunk = c ^ (row&7)
    const int srow = tid >> 3;
    const int csw = (tid & 7) ^ (srow & 7);
    const size_t srcOff = (size_t)srow * 1024 + (size_t)csw * 16;   // bytes
    auto stage = [&](int kc, int bi) {
        char* ba = &sAB[bi][0];
        #pragma unroll
        for (int j = 0; j < 4; ++j)
            async16(ba + j * 4096 + w * 1024, Ab + (size_t)j * 32768 + kc * 128 + srcOff);
        #pragma unroll
        for (int j = 0; j < 4; ++j)
            async16(ba + 16384 + j * 4096 + w * 1024, Bb + (size_t)j * 32768 + kc * 128 + srcOff);
    };

    f32x4 c[4][4];
    #pragma unroll
    for (int ii = 0; ii < 4; ++ii)
        #pragma unroll
        for (int jj = 0; jj < 4; ++jj) { f32x4 zv = {0.f, 0.f, 0.f, 0.f}; c[ii][jj] = zv; }

    stage(0, 0);
    for (int kc = 0; kc < 8; ++kc) {
        __syncthreads();                       // vmcnt(0)+lgkmcnt(0)+barrier: drains own DMA, syncs buf
        if (kc < 7) stage(kc + 1, (kc + 1) & 1);
        const char* tA = &sAB[kc & 1][0];
        const char* tB = &sAB[kc & 1][16384];
        #pragma unroll
        for (int ks = 0; ks < 2; ++ks) {
            short8 a[4], b[4];
            #pragma unroll
            for (int ii = 0; ii < 4; ++ii) {
                int row = wm + ii * 16 + l15;
                a[ii] = *(const short8*)(tA + row * 128 + (((ks * 4 + quad) ^ (l15 & 7)) * 16));
            }
            #pragma unroll
            for (int jj = 0; jj < 4; ++jj) {
                int row = wn + jj * 16 + l15;
                b[jj] = *(const short8*)(tB + row * 128 + (((ks * 4 + quad) ^ (l15 & 7)) * 16));
            }
            #pragma unroll
            for (int ii = 0; ii < 4; ++ii)
                #pragma unroll
                for (int jj = 0; jj < 4; ++jj)
                    c[ii][jj] = __builtin_amdgcn_mfma_f32_16x16x32_bf16(a[ii], b[jj], c[ii][jj], 0, 0, 0);
        }
    }

    // ---- epilogues ----
    #pragma unroll
    for (int ii = 0; ii < 4; ++ii) {
        const int mb = m0 + wm + ii * 16 + quad * 4;
        const int bb = mb >> 11;
        if (z == 0) {
            #pragma unroll
            for (int jj = 0; jj < 4; ++jj) {
                int ncol = n0 + wn + jj * 16 + l15;
                #pragma unroll
                for (int r = 0; r < 4; ++r)
                    qb[(size_t)(mb + r) * 512 + ncol] = f2bf(c[ii][jj][r]);
            }
        } else if (z == 1) {
            #pragma unroll
            for (int jj = 0; jj < 4; ++jj) {
                int d = n0 + wn + jj * 16 + l15;
                int pair = d >> 5, fh = (d >> 4) & 1, hid = (d >> 3) & 1, jq = d & 7;
                #pragma unroll
                for (int r = 0; r < 4; ++r) {
                    int s = (mb + r) & 2047;
                    int t = s >> 5, rr = swap23(s & 31);
                    kpack8[(((size_t)(bb * 64 + t) * 16 + pair) << 10)
                           + (hid * 32 + rr) * 16 + fh * 8 + jq] = f2fp8(c[ii][jj][r] * 32.f);
                }
            }
        } else {
            const int hh = (n0 + wn) >> 6;
            const int s = mb & 2047;
            #pragma unroll
            for (int jj = 0; jj < 4; ++jj) {
                int dh = jj * 16 + l15;
                ushort4v o;
                o[0] = f2bf(c[ii][jj][0]); o[1] = f2bf(c[ii][jj][1]);
                o[2] = f2bf(c[ii][jj][2]); o[3] = f2bf(c[ii][jj][3]);
                size_t blk = ((size_t)(bb * H_ + hh) * 64 + (s >> 5)) * 4
                           + ((dh >> 5) * 2 + ((s >> 4) & 1));
                *(ushort4v*)(vfrag + blk * 512 + (dh & 31) * 8 + ((s >> 3) & 1) * 256 + (s & 7)) = o;
            }
        }
    }
}

// ---------------- fused merge + output projection ----------------
__global__ __launch_bounds__(256) void gemm_out(const _Float16* __restrict__ Opart,
                                                const float* __restrict__ lpart,
                                                const unsigned short* __restrict__ Wdb,
                                                const float* __restrict__ bd,
                                                float* __restrict__ out) {
    __shared__ short sA[128 * 72];
    __shared__ short sB[128 * 72];
    const int m0 = blockIdx.x * 128, n0 = blockIdx.y * 128;
    const int tid = threadIdx.x, w = tid >> 6, lane = tid & 63, quad = lane >> 4, l15 = lane & 15;
    const int wm = (w >> 1) * 64, wn = (w & 1) * 64;
    f32x4 c[4][4];
    #pragma unroll
    for (int ii = 0; ii < 4; ++ii)
        #pragma unroll
        for (int jj = 0; jj < 4; ++jj) { f32x4 zv = {0.f, 0.f, 0.f, 0.f}; c[ii][jj] = zv; }
    for (int kc = 0; kc < 8; ++kc) {
        __syncthreads();
        #pragma unroll
        for (int j = 0; j < 4; ++j) {
            int i = tid + j * 256;
            int row = i >> 3, seg = i & 7;
            int gq = m0 + row;
            int b = gq >> 11, ql = gq & 2047, qq = ql & 127;
            int base = ((ql >> 7) << 5) | (kc << 2) | (b << 1);
            const _Float16* o0 = Opart + ((size_t)base << 13) + qq * 64 + seg * 8;
            float l = lpart[(size_t)base * 128 + qq] + lpart[(size_t)(base + 1) * 128 + qq];
            float inv = __builtin_amdgcn_rcpf(l);
            half8 v0 = *(const half8*)o0;
            half8 v1 = *(const half8*)(o0 + 8192);
            ushort8 ov;
            #pragma unroll
            for (int e = 0; e < 8; ++e)
                ov[e] = f2bf(((float)v0[e] + (float)v1[e]) * inv);
            *(ushort8*)&sA[row * 72 + seg * 8] = ov;
            *(ushort8*)&sB[row * 72 + seg * 8] =
                *(const ushort8*)(Wdb + (size_t)(n0 + row) * 512 + kc * 64 + seg * 8);
        }
        __syncthreads();
        #pragma unroll
        for (int ks = 0; ks < 2; ++ks) {
            short8 a[4], b2[4];
            #pragma unroll
            for (int ii = 0; ii < 4; ++ii)
                a[ii] = *(const short8*)&sA[(wm + ii * 16 + l15) * 72 + ks * 32 + quad * 8];
            #pragma unroll
            for (int jj = 0; jj < 4; ++jj)
                b2[jj] = *(const short8*)&sB[(wn + jj * 16 + l15) * 72 + ks * 32 + quad * 8];
            #pragma unroll
            for (int ii = 0; ii < 4; ++ii)
                #pragma unroll
                for (int jj = 0; jj < 4; ++jj)
                    c[ii][jj] = __builtin_amdgcn_mfma_f32_16x16x32_bf16(a[ii], b2[jj], c[ii][jj], 0, 0, 0);
        }
    }
    #pragma unroll
    for (int ii = 0; ii < 4; ++ii) {
        const int mb = m0 + wm + ii * 16 + quad * 4;
        #pragma unroll
        for (int jj = 0; jj < 4; ++jj) {
            int ncol = n0 + wn + jj * 16 + l15;
            float bias = bd[ncol];
            #pragma unroll
            for (int r = 0; r < 4; ++r)
                out[(size_t)(mb + r) * 512 + ncol] = c[ii][jj][r] + bias;
        }
    }
}

// ---------------- flash attention v19: one barrier/tile, 3x16KB ring, lean q-major epilogue ----------------
// Register ledger (R12 lesson): live state ~200 regs -> 2 blocks/CU is the residency cap; do NOT
// raise launch_bounds min-waves (3 waves/EU budget=170 -> accumulator spill, ~600MB scratch traffic).
__global__ __launch_bounds__(256, 2) void flash_attn(const unsigned short* __restrict__ qb,
                                                     const unsigned char* __restrict__ kpack8,
                                                     const unsigned short* __restrict__ vfrag,
                                                     const float* __restrict__ cbf_all,
                                                     const float* __restrict__ mixing,
                                                     _Float16* __restrict__ Opart,
                                                     float* __restrict__ lpart) {
    __shared__ char sK[3][16384];
    const int bid = blockIdx.x;
    const int half = bid & 1, b = (bid >> 1) & 1, h = (bid >> 2) & 7, qt = bid >> 5;
    const int tid = threadIdx.x, w = tid >> 6, lane = tid & 63;
    const int l31 = lane & 31, hi = lane >> 5;
    const int q0 = qt * 128 + w * 32;
    const unsigned short* vfb = vfrag + ((size_t)(b * H_ + h) * 64 + half * 32) * 2048;
    const float* cbfb = cbf_all + ((size_t)((b * 8 + h) * 64 + half * 32)) * 32 + hi * 16;
    const float* mixh = mixing + h * D_;
    const float SC = 1.44269504f / 4096.0f;

    long qq[32];
    {
        const unsigned short* qrow = qb + ((size_t)(b * L_) + q0 + l31) * D_ + hi * 8;
        #pragma unroll
        for (int i = 0; i < 32; ++i) {
            ushort8 qv = *(const ushort8*)(qrow + i * 16);
            float4v ma = *(const float4v*)(mixh + i * 16 + hi * 8);
            float4v mb = *(const float4v*)(mixh + i * 16 + hi * 8 + 4);
            float v[8];
            v[0] = bf2f(qv[0]) * ma[0] * 16.f;
            v[1] = bf2f(qv[1]) * ma[1] * 16.f;
            v[2] = bf2f(qv[2]) * ma[2] * 16.f;
            v[3] = bf2f(qv[3]) * ma[3] * 16.f;
            v[4] = bf2f(qv[4]) * mb[0] * 16.f;
            v[5] = bf2f(qv[5]) * mb[1] * 16.f;
            v[6] = bf2f(qv[6]) * mb[2] * 16.f;
            v[7] = bf2f(qv[7]) * mb[3] * 16.f;
            qq[i] = pack8fp8(v);
        }
    }
    asm volatile("s_waitcnt vmcnt(0)" ::: "memory");

    f32x16 acco0, acco1;
    #pragma unroll
    for (int i = 0; i < 16; ++i) { acco0[i] = 0.f; acco1[i] = 0.f; }
    float lsum = 0.f;
    f32x16 aA0, aB0, aA1, aB1;
    short8 av00, av01, av10, av11;
    float4v cbf0, cbf1, cbf2, cbf3;

    auto stageK2 = [&](int t, int bi) {
        const char* src = (const char*)kpack8 + (((size_t)(b * 64 + half * 32 + t)) << 14);
        char* dst = &sK[bi][0];
        #pragma unroll
        for (int ii = 0; ii < 4; ++ii)
            async16(dst + w * 1024 + ii * 4096, src + w * 1024 + ii * 4096 + (size_t)lane * 16);
    };
    auto ldV = [&](int t) {
        const unsigned short* vp = vfb + (size_t)t * 2048 + lane * 8;
        av00 = *(const short8*)(vp);
        av01 = *(const short8*)(vp + 512);
        av10 = *(const short8*)(vp + 1024);
        av11 = *(const short8*)(vp + 1536);
        asm volatile("" ::: "memory");
    };
    auto ldCB = [&](int t) {
        const float* cp = cbfb + t * 32;
        cbf0 = *(const float4v*)(cp);
        cbf1 = *(const float4v*)(cp + 4);
        cbf2 = *(const float4v*)(cp + 8);
        cbf3 = *(const float4v*)(cp + 12);
        asm volatile("" ::: "memory");
    };
    auto cbfv = [&](int R) -> float {
        return (R < 4) ? cbf0[R & 3] : (R < 8) ? cbf1[R & 3] : (R < 12) ? cbf2[R & 3] : cbf3[R & 3];
    };
    auto pack_pv = [&](const float* pex) {
        union { unsigned int u[4]; short8 s8; } P0, P1;
        #pragma unroll
        for (int j = 0; j < 4; ++j) {
            P0.u[j] = __builtin_amdgcn_perm(__float_as_uint(pex[2 * j + 1]) + 0x8000u,
                                            __float_as_uint(pex[2 * j]) + 0x8000u, 0x07060302u);
            P1.u[j] = __builtin_amdgcn_perm(__float_as_uint(pex[8 + 2 * j + 1]) + 0x8000u,
                                            __float_as_uint(pex[8 + 2 * j]) + 0x8000u, 0x07060302u);
        }
        acco0 = __builtin_amdgcn_mfma_f32_32x32x16_bf16(av00, P0.s8, acco0, 0, 0, 0);
        acco0 = __builtin_amdgcn_mfma_f32_32x32x16_bf16(av01, P1.s8, acco0, 0, 0, 0);
        acco1 = __builtin_amdgcn_mfma_f32_32x32x16_bf16(av10, P0.s8, acco1, 0, 0, 0);
        acco1 = __builtin_amdgcn_mfma_f32_32x32x16_bf16(av11, P1.s8, acco1, 0, 0, 0);
    };
    auto tile_fused = [&](const char* buf, int T, f32x16& CA, f32x16& CB,
                          const f32x16& PA, const f32x16& PB) {
        __builtin_amdgcn_s_setprio(1);
        float pex[16];
        float lsA = 0.f, lsB = 0.f;
        #pragma unroll
        for (int fp = 0; fp < 16; ++fp) {
            const long* ap = (const long*)&buf[fp * 1024 + lane * 16];
            long a0 = ap[0], a1 = ap[1];
            CA = __builtin_amdgcn_mfma_f32_32x32x16_fp8_fp8(a0, qq[2 * fp], CA, 0, 0, 0);
            CB = __builtin_amdgcn_mfma_f32_32x32x16_fp8_fp8(a1, qq[2 * fp + 1], CB, 0, 0, 0);
            if (fp < 8) {
                float x0 = fmaf(PA[2 * fp] + PB[2 * fp], SC, cbfv(2 * fp));
                float x1 = fmaf(PA[2 * fp + 1] + PB[2 * fp + 1], SC, cbfv(2 * fp + 1));
                float e0, e1;
                asm("v_exp_f32 %0, %1" : "=v"(e0) : "v"(x0));
                asm("v_exp_f32 %0, %1" : "=v"(e1) : "v"(x1));
                pex[2 * fp] = e0; pex[2 * fp + 1] = e1;
                lsA += e0; lsB += e1;
            }
            if (fp == 8) { lsum += lsA + lsB; pack_pv(pex); }
            if (fp == 9)  ldV(T);
            if (fp == 10) ldCB(T);
        }
        __builtin_amdgcn_s_setprio(0);
    };
    auto tile_plain = [&](const char* buf, int T, f32x16& CA, f32x16& CB) {
        __builtin_amdgcn_s_setprio(1);
        #pragma unroll
        for (int fp = 0; fp < 16; ++fp) {
            const long* ap = (const long*)&buf[fp * 1024 + lane * 16];
            long a0 = ap[0], a1 = ap[1];
            CA = __builtin_amdgcn_mfma_f32_32x32x16_fp8_fp8(a0, qq[2 * fp], CA, 0, 0, 0);
            CB = __builtin_amdgcn_mfma_f32_32x32x16_fp8_fp8(a1, qq[2 * fp + 1], CB, 0, 0, 0);
            if (fp == 9)  ldV(T);
            if (fp == 10) ldCB(T);
        }
        __builtin_amdgcn_s_setprio(0);
    };
    auto sm_pv = [&](const f32x16& PA, const f32x16& PB) {
        float pex[16];
        float lsA = 0.f, lsB = 0.f;
        #pragma unroll
        for (int R = 0; R < 16; R += 2) {
            float x0 = fmaf(PA[R] + PB[R], SC, cbfv(R));
            float x1 = fmaf(PA[R + 1] + PB[R + 1], SC, cbfv(R + 1));
            float e0, e1;
            asm("v_exp_f32 %0, %1" : "=v"(e0) : "v"(x0));
            asm("v_exp_f32 %0, %1" : "=v"(e1) : "v"(x1));
            pex[R] = e0; pex[R + 1] = e1;
            lsA += e0; lsB += e1;
        }
        lsum += lsA + lsB;
        pack_pv(pex);
    };
    auto zero16 = [](f32x16& v) {
        #pragma unroll
        for (int i = 0; i < 16; ++i) v[i] = 0.f;
    };

    // ---- prologue: 2 K-tiles in flight ----
    stageK2(0, 0); stageK2(1, 1);

    // ---- phase 0 (bank0, buf0) ----
    zero16(aA0); zero16(aB0);
    asm volatile("s_waitcnt vmcnt(4)" ::: "memory");
    __builtin_amdgcn_s_barrier();
    tile_plain(&sK[0][0], 0, aA0, aB0);
    stageK2(2, 2);

    // ---- phases 1..30 (ring: tile t -> buf t%3; stage t+2 -> buf (t+2)%3) ----
    int cur = 1;
    for (int t = 1; t <= 30; t += 2) {
        zero16(aA1); zero16(aB1);
        asm volatile("s_waitcnt vmcnt(4)" ::: "memory");
        __builtin_amdgcn_s_barrier();
        tile_fused(&sK[cur][0], t, aA1, aB1, aA0, aB0);
        if (t + 2 <= 31) stageK2(t + 2, (cur + 2 >= 3) ? cur - 1 : cur + 2);
        cur = (cur == 2) ? 0 : cur + 1;

        zero16(aA0); zero16(aB0);
        asm volatile("s_waitcnt vmcnt(4)" ::: "memory");
        __builtin_amdgcn_s_barrier();
        tile_fused(&sK[cur][0], t + 1, aA0, aB0, aA1, aB1);
        if (t + 3 <= 31) stageK2(t + 3, (cur + 2 >= 3) ? cur - 1 : cur + 2);
        cur = (cur == 2) ? 0 : cur + 1;
    }

    // ---- phase 31 (bank1, buf cur=1; deferred softmax of 30 in bank0) ----
    {
        zero16(aA1); zero16(aB1);
        asm volatile("s_waitcnt vmcnt(0)" ::: "memory");
        __builtin_amdgcn_s_barrier();
        tile_fused(&sK[cur][0], 31, aA1, aB1, aA0, aB0);
        asm volatile("s_waitcnt vmcnt(0)" ::: "memory");
        sm_pv(aA1, aB1);
    }

    // ---- epilogue: lsum; O^T -> q-major via sO = sK[0] (free after the phase-31 barrier);
    // b64-packed writes; intra-wave LDS RAW only (wave w owns rows [32w,32w+32)) ----
    lsum += __shfl_xor(lsum, 32);
    if (hi == 0) lpart[(size_t)bid * 128 + w * 32 + l31] = lsum;
    {
        _Float16* sO = (_Float16*)&sK[0][0];           // [128][72] halves (stride 144 B)
        const int q = w * 32 + l31;
        #pragma unroll
        for (int u = 0; u < 4; ++u) {
            half4 v0, v1;
            v0[0] = (_Float16)acco0[4 * u];     v0[1] = (_Float16)acco0[4 * u + 1];
            v0[2] = (_Float16)acco0[4 * u + 2]; v0[3] = (_Float16)acco0[4 * u + 3];
            v1[0] = (_Float16)acco1[4 * u];     v1[1] = (_Float16)acco1[4 * u + 1];
            v1[2] = (_Float16)acco1[4 * u + 2]; v1[3] = (_Float16)acco1[4 * u + 3];
            *(half4*)&sO[q * 72 + u * 8 + 4 * hi]      = v0;   // dh = 8u + 4hi + 0..3
            *(half4*)&sO[q * 72 + 32 + u * 8 + 4 * hi] = v1;
        }
        const int qd = tid >> 1, hf = tid & 1;
        _Float16* dst = Opart + ((size_t)bid << 13) + qd * 64 + hf * 32;
        const _Float16* srcp = sO + qd * 72 + hf * 32;
        #pragma unroll
        for (int k = 0; k < 4; ++k)
            *(half8*)(dst + k * 8) = *(const half8*)(srcp + k * 8);
    }
}

extern "C" void kernel_launch(void* const* d_in, const int* in_sizes, int n_in,
                              void* d_out, int out_size, void* d_ws, size_t ws_size,
                              hipStream_t stream) {
    (void)in_sizes; (void)n_in; (void)out_size; (void)ws_size;
    const float* x      = (const float*)d_in[0];
    const float* Wq     = (const float*)d_in[1];
    const float* Wk     = (const float*)d_in[2];
    const float* Wv     = (const float*)d_in[3];
    const float* Wb     = (const float*)d_in[4];
    const float* mixing = (const float*)d_in[5];
    const float* Wd     = (const float*)d_in[6];
    const float* bd     = (const float*)d_in[7];
    float* out = (float*)d_out;

    char* ws = (char*)d_ws;
    const size_t MiB = 1048576;
    unsigned short* xb     = (unsigned short*)(ws);                  // [0,4) MiB
    unsigned short* qb     = (unsigned short*)(ws + 4 * MiB);        // [4,8) bf16 q row-major
    unsigned char*  kpack8 = (unsigned char*)(ws + 8 * MiB);         // [8,10) fp8 K A-frags (x32)
    unsigned short* vfrag  = (unsigned short*)(ws + 10 * MiB);       // [10,14)
    unsigned short* Wqb    = (unsigned short*)(ws + 18 * MiB);
    unsigned short* Wkb    = (unsigned short*)(ws + 18 * MiB + 512 * 1024);
    unsigned short* Wvb    = (unsigned short*)(ws + 19 * MiB);
    unsigned short* Wdb    = (unsigned short*)(ws + 19 * MiB + 512 * 1024);
    float* cbuf            = (float*)(ws + 20 * MiB);                // 128 KB (f32 frag-major)
    float* lpart           = (float*)(ws + 20 * MiB + 256 * 1024);   // 256 KB
    _Float16* Opart        = (_Float16*)(ws + 21 * MiB);             // [21,29) 8 MB, q-major

    cvt_cb<<<4096, 256, 0, stream>>>(x, Wq, Wk, Wv, Wd, Wb, xb, Wqb, Wkb, Wvb, Wdb, cbuf);
    gemm_qkv<<<dim3(32, 4, 3), 256, 0, stream>>>(xb, Wqb, Wkb, Wvb, qb, kpack8, vfrag);
    flash_attn<<<512, 256, 0, stream>>>(qb, kpack8, vfrag, cbuf, mixing, Opart, lpart);
    gemm_out<<<dim3(32, 4), 256, 0, stream>>>(Opart, lpart, Wdb, bd, out);
}

// Round 14
// 182.661 us; speedup vs baseline: 2.0885x; 1.0521x over previous
//
#include <hip/hip_runtime.h>

#define B_ 2
#define L_ 2048
#define D_ 512
#define H_ 8
#define S_ 2048

typedef __attribute__((ext_vector_type(8))) short short8;
typedef __attribute__((ext_vector_type(8))) unsigned short ushort8;
typedef __attribute__((ext_vector_type(4))) unsigned short ushort4v;
typedef __attribute__((ext_vector_type(4))) float f32x4;
typedef __attribute__((ext_vector_type(16))) float f32x16;
typedef __attribute__((ext_vector_type(4))) float float4v;
typedef __attribute__((ext_vector_type(8))) _Float16 half8;
typedef __attribute__((ext_vector_type(4))) _Float16 half4;
typedef __attribute__((ext_vector_type(4))) int int4v;
typedef __attribute__((ext_vector_type(8))) int int8v;

__device__ __forceinline__ unsigned short f2bf(float f) {
    unsigned u = __float_as_uint(f);
    u += 0x7FFF + ((u >> 16) & 1);   // RTNE
    return (unsigned short)(u >> 16);
}
__device__ __forceinline__ float bf2f(unsigned short s) {
    return __uint_as_float(((unsigned)s) << 16);
}
__device__ __forceinline__ unsigned char f2fp8(float f) {
    return (unsigned char)(__builtin_amdgcn_cvt_pk_fp8_f32(f, f, 0, false) & 0xff);
}
__device__ __forceinline__ long pack8fp8(const float* v) {
    int lo = __builtin_amdgcn_cvt_pk_fp8_f32(v[0], v[1], 0, false);
    lo = __builtin_amdgcn_cvt_pk_fp8_f32(v[2], v[3], lo, true);
    int hi = __builtin_amdgcn_cvt_pk_fp8_f32(v[4], v[5], 0, false);
    hi = __builtin_amdgcn_cvt_pk_fp8_f32(v[6], v[7], hi, true);
    union { int i[2]; long l; } u;
    u.i[0] = lo; u.i[1] = hi;
    return u.l;
}
__device__ __forceinline__ int swap23(int x) {
    return (x & ~12) | ((x & 4) << 1) | ((x & 8) >> 1);
}
// async global->LDS, 16B per lane; LDS arg = WAVE-UNIFORM base (HW adds lane*16); global arg per-lane
__device__ __forceinline__ void async16(void* lds, const void* g) {
    __builtin_amdgcn_global_load_lds(
        (const __attribute__((address_space(1))) void*)(g),
        (__attribute__((address_space(3))) void*)(lds), 16, 0, 0);
}

// ---------------- fused: fp32->bf16 converts + content bias (frag-major f32, log2e/8-scaled) ----------------
__global__ __launch_bounds__(256) void cvt_cb(const float* __restrict__ x,
                                              const float* __restrict__ w0, const float* __restrict__ w1,
                                              const float* __restrict__ w2, const float* __restrict__ w3,
                                              const float* __restrict__ Wb,
                                              unsigned short* __restrict__ xb,
                                              unsigned short* __restrict__ d0, unsigned short* __restrict__ d1,
                                              unsigned short* __restrict__ d2, unsigned short* __restrict__ d3,
                                              float* __restrict__ cbf) {
    if (blockIdx.x < 3072) {
        int i = blockIdx.x * 256 + threadIdx.x;
        const float* s;
        unsigned short* d;
        int idx;
        if (i < 524288) { s = x; d = xb; idx = i; }
        else {
            int off = i - 524288;
            int wsel = off >> 16; idx = off & 65535;
            s = (wsel == 0) ? w0 : (wsel == 1) ? w1 : (wsel == 2) ? w2 : w3;
            d = (wsel == 0) ? d0 : (wsel == 1) ? d1 : (wsel == 2) ? d2 : d3;
        }
        float4v v = *(const float4v*)(s + (size_t)idx * 4);
        ushort4v o;
        o[0] = f2bf(v[0]); o[1] = f2bf(v[1]); o[2] = f2bf(v[2]); o[3] = f2bf(v[3]);
        *(ushort4v*)(d + (size_t)idx * 4) = o;
    } else {
        const int tid = threadIdx.x, w = tid >> 6, lane = tid & 63;
        const int row = (blockIdx.x - 3072) * 4 + w;
        const int h = lane >> 3, seg = lane & 7;
        const float* xp = x + (size_t)row * 512 + seg * 64;
        const float* wp = Wb + (size_t)h * 512 + seg * 64;
        float acc = 0.f;
        #pragma unroll
        for (int j = 0; j < 16; ++j) {
            float4v xv = *(const float4v*)(xp + j * 4);
            float4v wv = *(const float4v*)(wp + j * 4);
            acc += xv[0] * wv[0] + xv[1] * wv[1] + xv[2] * wv[2] + xv[3] * wv[3];
        }
        acc += __shfl_xor(acc, 1);
        acc += __shfl_xor(acc, 2);
        acc += __shfl_xor(acc, 4);
        if (seg == 0) {
            int b = row >> 11, s = row & 2047;
            int T = s >> 5, off = s & 31;
            int r2 = off & 3, k = off >> 2;
            int u = (k & 1) + ((k >> 2) << 1), hi2 = (k >> 1) & 1;
            int R = 4 * u + r2;
            cbf[((size_t)((b * 8 + h) * 64 + T)) * 32 + hi2 * 16 + R] = acc * 0.125f * 1.44269504f;
        }
    }
}

// ---------------- q,k,v projections: async-DMA staged core (m97 pattern), 1 barrier/kc ----------------
// LDS tiles linear [row 128][chunk 8][16B]; chunk c of row r holds GLOBAL chunk (c ^ (r&7))
// (rule #21: linear dest + pre-swizzled source + swizzled read). Double-buffered: 64 KB.
// K layout CHANGED for mfma_scale 32x32x64 A-frags: byte(d,s) = tile*16K + (d>>6)*2048
//   + ((d>>4)&1)*1024 + (swap23(s&31) + ((d>>5)&1)*32)*16 + (d&15)   [bijective over 16 KB]
__global__ __launch_bounds__(256) void gemm_qkv(const unsigned short* __restrict__ xb,
                                                const unsigned short* __restrict__ Wqb,
                                                const unsigned short* __restrict__ Wkb,
                                                const unsigned short* __restrict__ Wvb,
                                                unsigned short* __restrict__ qb,
                                                unsigned char* __restrict__ kpack8,
                                                unsigned short* __restrict__ vfrag) {
    __shared__ char sAB[2][32768];   // [buf][ A 16KB | B 16KB ]
    const int m0 = blockIdx.x * 128, n0 = blockIdx.y * 128, z = blockIdx.z;
    const unsigned short* Bsel = (z == 0) ? Wqb : ((z == 1) ? Wkb : Wvb);
    const int tid = threadIdx.x, w = tid >> 6, lane = tid & 63, quad = lane >> 4, l15 = lane & 15;
    const int wm = (w >> 1) * 64, wn = (w & 1) * 64;
    const char* Ab = (const char*)(xb + (size_t)m0 * 512);
    const char* Bb = (const char*)(Bsel + (size_t)n0 * 512);
    const int srow = tid >> 3;
    const int csw = (tid & 7) ^ (srow & 7);
    const size_t srcOff = (size_t)srow * 1024 + (size_t)csw * 16;   // bytes
    auto stage = [&](int kc, int bi) {
        char* ba = &sAB[bi][0];
        #pragma unroll
        for (int j = 0; j < 4; ++j)
            async16(ba + j * 4096 + w * 1024, Ab + (size_t)j * 32768 + kc * 128 + srcOff);
        #pragma unroll
        for (int j = 0; j < 4; ++j)
            async16(ba + 16384 + j * 4096 + w * 1024, Bb + (size_t)j * 32768 + kc * 128 + srcOff);
    };

    f32x4 c[4][4];
    #pragma unroll
    for (int ii = 0; ii < 4; ++ii)
        #pragma unroll
        for (int jj = 0; jj < 4; ++jj) { f32x4 zv = {0.f, 0.f, 0.f, 0.f}; c[ii][jj] = zv; }

    stage(0, 0);
    for (int kc = 0; kc < 8; ++kc) {
        __syncthreads();
        if (kc < 7) stage(kc + 1, (kc + 1) & 1);
        const char* tA = &sAB[kc & 1][0];
        const char* tB = &sAB[kc & 1][16384];
        #pragma unroll
        for (int ks = 0; ks < 2; ++ks) {
            short8 a[4], b[4];
            #pragma unroll
            for (int ii = 0; ii < 4; ++ii) {
                int row = wm + ii * 16 + l15;
                a[ii] = *(const short8*)(tA + row * 128 + (((ks * 4 + quad) ^ (l15 & 7)) * 16));
            }
            #pragma unroll
            for (int jj = 0; jj < 4; ++jj) {
                int row = wn + jj * 16 + l15;
                b[jj] = *(const short8*)(tB + row * 128 + (((ks * 4 + quad) ^ (l15 & 7)) * 16));
            }
            #pragma unroll
            for (int ii = 0; ii < 4; ++ii)
                #pragma unroll
                for (int jj = 0; jj < 4; ++jj)
                    c[ii][jj] = __builtin_amdgcn_mfma_f32_16x16x32_bf16(a[ii], b[jj], c[ii][jj], 0, 0, 0);
        }
    }

    // ---- epilogues ----
    #pragma unroll
    for (int ii = 0; ii < 4; ++ii) {
        const int mb = m0 + wm + ii * 16 + quad * 4;
        const int bb = mb >> 11;
        if (z == 0) {
            #pragma unroll
            for (int jj = 0; jj < 4; ++jj) {
                int ncol = n0 + wn + jj * 16 + l15;
                #pragma unroll
                for (int r = 0; r < 4; ++r)
                    qb[(size_t)(mb + r) * 512 + ncol] = f2bf(c[ii][jj][r]);
            }
        } else if (z == 1) {
            #pragma unroll
            for (int jj = 0; jj < 4; ++jj) {
                int d = n0 + wn + jj * 16 + l15;
                int f = d >> 6, ch = (d >> 4) & 1, kh = (d >> 5) & 1, j15 = d & 15;
                #pragma unroll
                for (int r = 0; r < 4; ++r) {
                    int s = (mb + r) & 2047;
                    int t = s >> 5, rr = swap23(s & 31);
                    kpack8[((size_t)(bb * 64 + t) << 14)
                           + f * 2048 + ch * 1024 + (kh * 32 + rr) * 16 + j15] = f2fp8(c[ii][jj][r] * 32.f);
                }
            }
        } else {
            const int hh = (n0 + wn) >> 6;
            const int s = mb & 2047;
            #pragma unroll
            for (int jj = 0; jj < 4; ++jj) {
                int dh = jj * 16 + l15;
                ushort4v o;
                o[0] = f2bf(c[ii][jj][0]); o[1] = f2bf(c[ii][jj][1]);
                o[2] = f2bf(c[ii][jj][2]); o[3] = f2bf(c[ii][jj][3]);
                size_t blk = ((size_t)(bb * H_ + hh) * 64 + (s >> 5)) * 4
                           + ((dh >> 5) * 2 + ((s >> 4) & 1));
                *(ushort4v*)(vfrag + blk * 512 + (dh & 31) * 8 + ((s >> 3) & 1) * 256 + (s & 7)) = o;
            }
        }
    }
}

// ---------------- fused merge + output projection ----------------
__global__ __launch_bounds__(256) void gemm_out(const _Float16* __restrict__ Opart,
                                                const float* __restrict__ lpart,
                                                const unsigned short* __restrict__ Wdb,
                                                const float* __restrict__ bd,
                                                float* __restrict__ out) {
    __shared__ short sA[128 * 72];
    __shared__ short sB[128 * 72];
    const int m0 = blockIdx.x * 128, n0 = blockIdx.y * 128;
    const int tid = threadIdx.x, w = tid >> 6, lane = tid & 63, quad = lane >> 4, l15 = lane & 15;
    const int wm = (w >> 1) * 64, wn = (w & 1) * 64;
    f32x4 c[4][4];
    #pragma unroll
    for (int ii = 0; ii < 4; ++ii)
        #pragma unroll
        for (int jj = 0; jj < 4; ++jj) { f32x4 zv = {0.f, 0.f, 0.f, 0.f}; c[ii][jj] = zv; }
    for (int kc = 0; kc < 8; ++kc) {
        __syncthreads();
        #pragma unroll
        for (int j = 0; j < 4; ++j) {
            int i = tid + j * 256;
            int row = i >> 3, seg = i & 7;
            int gq = m0 + row;
            int b = gq >> 11, ql = gq & 2047, qq = ql & 127;
            int base = ((ql >> 7) << 5) | (kc << 2) | (b << 1);
            const _Float16* o0 = Opart + ((size_t)base << 13) + qq * 64 + seg * 8;
            float l = lpart[(size_t)base * 128 + qq] + lpart[(size_t)(base + 1) * 128 + qq];
            float inv = __builtin_amdgcn_rcpf(l);
            half8 v0 = *(const half8*)o0;
            half8 v1 = *(const half8*)(o0 + 8192);
            ushort8 ov;
            #pragma unroll
            for (int e = 0; e < 8; ++e)
                ov[e] = f2bf(((float)v0[e] + (float)v1[e]) * inv);
            *(ushort8*)&sA[row * 72 + seg * 8] = ov;
            *(ushort8*)&sB[row * 72 + seg * 8] =
                *(const ushort8*)(Wdb + (size_t)(n0 + row) * 512 + kc * 64 + seg * 8);
        }
        __syncthreads();
        #pragma unroll
        for (int ks = 0; ks < 2; ++ks) {
            short8 a[4], b2[4];
            #pragma unroll
            for (int ii = 0; ii < 4; ++ii)
                a[ii] = *(const short8*)&sA[(wm + ii * 16 + l15) * 72 + ks * 32 + quad * 8];
            #pragma unroll
            for (int jj = 0; jj < 4; ++jj)
                b2[jj] = *(const short8*)&sB[(wn + jj * 16 + l15) * 72 + ks * 32 + quad * 8];
            #pragma unroll
            for (int ii = 0; ii < 4; ++ii)
                #pragma unroll
                for (int jj = 0; jj < 4; ++jj)
                    c[ii][jj] = __builtin_amdgcn_mfma_f32_16x16x32_bf16(a[ii], b2[jj], c[ii][jj], 0, 0, 0);
        }
    }
    #pragma unroll
    for (int ii = 0; ii < 4; ++ii) {
        const int mb = m0 + wm + ii * 16 + quad * 4;
        #pragma unroll
        for (int jj = 0; jj < 4; ++jj) {
            int ncol = n0 + wn + jj * 16 + l15;
            float bias = bd[ncol];
            #pragma unroll
            for (int r = 0; r < 4; ++r)
                out[(size_t)(mb + r) * 512 + ncol] = c[ii][jj][r] + bias;
        }
    }
}

// ---------------- flash attention v21: MX-scaled 32x32x64 fp8 QK (unit scales), v19 schedule ----------------
// QK per tile: 8 x mfma_scale_f32_32x32x64_f8f6f4 (2x fp8 rate) instead of 32 x 32x32x16 — pipe
// demand per CU-tile 2304 -> ~1280 cyc. Single S-accumulator per bank (K=64 covers both k-halves).
// A-frag: lane l = swap23-row(l&31) + khalf(l>>5)*32, 32 k-bytes as two stride-16 b128 chunks.
// B-frag (Q): lane l31 = q-col, k = hi*32+[0,32) per 64-k frag. C layout shape-determined -> swap23
// PV chain unchanged. Scales = 0x7F (1.0) -> numerics identical to v19. FIFO/staging verbatim.
// Register ledger: ~170 live (do NOT raise launch_bounds min-waves — R12 spill lesson).
__global__ __launch_bounds__(256, 2) void flash_attn(const unsigned short* __restrict__ qb,
                                                     const unsigned char* __restrict__ kpack8,
                                                     const unsigned short* __restrict__ vfrag,
                                                     const float* __restrict__ cbf_all,
                                                     const float* __restrict__ mixing,
                                                     _Float16* __restrict__ Opart,
                                                     float* __restrict__ lpart) {
    __shared__ char sK[3][16384];
    const int bid = blockIdx.x;
    const int half = bid & 1, b = (bid >> 1) & 1, h = (bid >> 2) & 7, qt = bid >> 5;
    const int tid = threadIdx.x, w = tid >> 6, lane = tid & 63;
    const int l31 = lane & 31, hi = lane >> 5;
    const int q0 = qt * 128 + w * 32;
    const unsigned short* vfb = vfrag + ((size_t)(b * H_ + h) * 64 + half * 32) * 2048;
    const float* cbfb = cbf_all + ((size_t)((b * 8 + h) * 64 + half * 32)) * 32 + hi * 16;
    const float* mixh = mixing + h * D_;
    const float SC = 1.44269504f / 4096.0f;   // log2e / (16*32*8)

    // ---- Q: bf16 rows -> x mixing (f32) -> fp8 B-frags for 32x32x64 (frag f: d = f*64 + hi*32 + [0,32)) ----
    int8v qf8v[8];
    {
        const unsigned short* qrow = qb + ((size_t)(b * L_) + q0 + l31) * D_;
        #pragma unroll
        for (int f = 0; f < 8; ++f) {
            union { long l[4]; int8v v; } qu;
            #pragma unroll
            for (int g = 0; g < 4; ++g) {
                int d0 = f * 64 + hi * 32 + g * 8;
                ushort8 qv = *(const ushort8*)(qrow + d0);
                float4v ma = *(const float4v*)(mixh + d0);
                float4v mb2 = *(const float4v*)(mixh + d0 + 4);
                float v[8];
                v[0] = bf2f(qv[0]) * ma[0] * 16.f;
                v[1] = bf2f(qv[1]) * ma[1] * 16.f;
                v[2] = bf2f(qv[2]) * ma[2] * 16.f;
                v[3] = bf2f(qv[3]) * ma[3] * 16.f;
                v[4] = bf2f(qv[4]) * mb2[0] * 16.f;
                v[5] = bf2f(qv[5]) * mb2[1] * 16.f;
                v[6] = bf2f(qv[6]) * mb2[2] * 16.f;
                v[7] = bf2f(qv[7]) * mb2[3] * 16.f;
                qu.l[g] = pack8fp8(v);
            }
            qf8v[f] = qu.v;
        }
    }
    asm volatile("s_waitcnt vmcnt(0)" ::: "memory");

    f32x16 acco0, acco1;
    #pragma unroll
    for (int i = 0; i < 16; ++i) { acco0[i] = 0.f; acco1[i] = 0.f; }
    float lsum = 0.f;
    f32x16 aS0, aS1;                     // S accumulators, 2 banks (even/odd tile)
    short8 av00, av01, av10, av11;
    float4v cbf0, cbf1, cbf2, cbf3;

    auto stageK2 = [&](int t, int bi) {
        const char* src = (const char*)kpack8 + (((size_t)(b * 64 + half * 32 + t)) << 14);
        char* dst = &sK[bi][0];
        #pragma unroll
        for (int ii = 0; ii < 4; ++ii)
            async16(dst + w * 1024 + ii * 4096, src + w * 1024 + ii * 4096 + (size_t)lane * 16);
    };
    auto ldV = [&](int t) {
        const unsigned short* vp = vfb + (size_t)t * 2048 + lane * 8;
        av00 = *(const short8*)(vp);
        av01 = *(const short8*)(vp + 512);
        av10 = *(const short8*)(vp + 1024);
        av11 = *(const short8*)(vp + 1536);
        asm volatile("" ::: "memory");
    };
    auto ldCB = [&](int t) {
        const float* cp = cbfb + t * 32;
        cbf0 = *(const float4v*)(cp);
        cbf1 = *(const float4v*)(cp + 4);
        cbf2 = *(const float4v*)(cp + 8);
        cbf3 = *(const float4v*)(cp + 12);
        asm volatile("" ::: "memory");
    };
    auto cbfv = [&](int R) -> float {
        return (R < 4) ? cbf0[R & 3] : (R < 8) ? cbf1[R & 3] : (R < 12) ? cbf2[R & 3] : cbf3[R & 3];
    };
    auto pack_pv = [&](const float* pex) {
        union { unsigned int u[4]; short8 s8; } P0, P1;
        #pragma unroll
        for (int j = 0; j < 4; ++j) {
            P0.u[j] = __builtin_amdgcn_perm(__float_as_uint(pex[2 * j + 1]) + 0x8000u,
                                            __float_as_uint(pex[2 * j]) + 0x8000u, 0x07060302u);
            P1.u[j] = __builtin_amdgcn_perm(__float_as_uint(pex[8 + 2 * j + 1]) + 0x8000u,
                                            __float_as_uint(pex[8 + 2 * j]) + 0x8000u, 0x07060302u);
        }
        acco0 = __builtin_amdgcn_mfma_f32_32x32x16_bf16(av00, P0.s8, acco0, 0, 0, 0);
        acco0 = __builtin_amdgcn_mfma_f32_32x32x16_bf16(av01, P1.s8, acco0, 0, 0, 0);
        acco1 = __builtin_amdgcn_mfma_f32_32x32x16_bf16(av10, P0.s8, acco1, 0, 0, 0);
        acco1 = __builtin_amdgcn_mfma_f32_32x32x16_bf16(av11, P1.s8, acco1, 0, 0, 0);
    };
    // one K=64 A-frag from LDS: two stride-16 b128 chunks (conflict-free)
    auto ldA = [&](const char* buf, int f) -> int8v {
        int4v lo = *(const int4v*)&buf[f * 2048 + lane * 16];
        int4v ah = *(const int4v*)&buf[f * 2048 + 1024 + lane * 16];
        int8v a;
        a[0] = lo[0]; a[1] = lo[1]; a[2] = lo[2]; a[3] = lo[3];
        a[4] = ah[0]; a[5] = ah[1]; a[6] = ah[2]; a[7] = ah[3];
        return a;
    };
    auto tile_fused = [&](const char* buf, int T, f32x16& C, const f32x16& P) {
        __builtin_amdgcn_s_setprio(1);
        float pex[16];
        float lsA = 0.f, lsB = 0.f;
        #pragma unroll
        for (int f = 0; f < 8; ++f) {
            int8v a = ldA(buf, f);
            C = __builtin_amdgcn_mfma_scale_f32_32x32x64_f8f6f4(
                    a, qf8v[f], C, 0, 0, 0, 0x7F7F7F7F, 0, 0x7F7F7F7F);
            if (f < 4) {
                #pragma unroll
                for (int j = 0; j < 4; j += 2) {
                    int R = 4 * f + j;
                    float x0 = fmaf(P[R], SC, cbfv(R));
                    float x1 = fmaf(P[R + 1], SC, cbfv(R + 1));
                    float e0, e1;
                    asm("v_exp_f32 %0, %1" : "=v"(e0) : "v"(x0));
                    asm("v_exp_f32 %0, %1" : "=v"(e1) : "v"(x1));
                    pex[R] = e0; pex[R + 1] = e1;
                    lsA += e0; lsB += e1;
                }
            }
            if (f == 4) { lsum += lsA + lsB; pack_pv(pex); }
            if (f == 5)  ldV(T);
            if (f == 6)  ldCB(T);
        }
        __builtin_amdgcn_s_setprio(0);
    };
    auto tile_plain = [&](const char* buf, int T, f32x16& C) {
        __builtin_amdgcn_s_setprio(1);
        #pragma unroll
        for (int f = 0; f < 8; ++f) {
            int8v a = ldA(buf, f);
            C = __builtin_amdgcn_mfma_scale_f32_32x32x64_f8f6f4(
                    a, qf8v[f], C, 0, 0, 0, 0x7F7F7F7F, 0, 0x7F7F7F7F);
            if (f == 5) ldV(T);
            if (f == 6) ldCB(T);
        }
        __builtin_amdgcn_s_setprio(0);
    };
    auto sm_pv = [&](const f32x16& P) {
        float pex[16];
        float lsA = 0.f, lsB = 0.f;
        #pragma unroll
        for (int R = 0; R < 16; R += 2) {
            float x0 = fmaf(P[R], SC, cbfv(R));
            float x1 = fmaf(P[R + 1], SC, cbfv(R + 1));
            float e0, e1;
            asm("v_exp_f32 %0, %1" : "=v"(e0) : "v"(x0));
            asm("v_exp_f32 %0, %1" : "=v"(e1) : "v"(x1));
            pex[R] = e0; pex[R + 1] = e1;
            lsA += e0; lsB += e1;
        }
        lsum += lsA + lsB;
        pack_pv(pex);
    };
    auto zero16 = [](f32x16& v) {
        #pragma unroll
        for (int i = 0; i < 16; ++i) v[i] = 0.f;
    };

    // ---- prologue: 2 K-tiles in flight ----
    stageK2(0, 0); stageK2(1, 1);

    // ---- phase 0 (bank0, buf0) ----
    zero16(aS0);
    asm volatile("s_waitcnt vmcnt(4)" ::: "memory");
    __builtin_amdgcn_s_barrier();
    tile_plain(&sK[0][0], 0, aS0);
    stageK2(2, 2);

    // ---- phases 1..30 (ring: tile t -> buf t%3; stage t+2 -> buf (t+2)%3) ----
    int cur = 1;
    for (int t = 1; t <= 30; t += 2) {
        zero16(aS1);
        asm volatile("s_waitcnt vmcnt(4)" ::: "memory");
        __builtin_amdgcn_s_barrier();
        tile_fused(&sK[cur][0], t, aS1, aS0);
        if (t + 2 <= 31) stageK2(t + 2, (cur + 2 >= 3) ? cur - 1 : cur + 2);
        cur = (cur == 2) ? 0 : cur + 1;

        zero16(aS0);
        asm volatile("s_waitcnt vmcnt(4)" ::: "memory");
        __builtin_amdgcn_s_barrier();
        tile_fused(&sK[cur][0], t + 1, aS0, aS1);
        if (t + 3 <= 31) stageK2(t + 3, (cur + 2 >= 3) ? cur - 1 : cur + 2);
        cur = (cur == 2) ? 0 : cur + 1;
    }

    // ---- phase 31 (bank1, buf cur=1; deferred softmax of 30 in bank0) ----
    {
        zero16(aS1);
        asm volatile("s_waitcnt vmcnt(0)" ::: "memory");
        __builtin_amdgcn_s_barrier();
        tile_fused(&sK[cur][0], 31, aS1, aS0);
        asm volatile("s_waitcnt vmcnt(0)" ::: "memory");
        sm_pv(aS1);
    }

    // ---- epilogue: lsum; O^T -> q-major via sO = sK[0] (free after the phase-31 barrier);
    // b64-packed writes; intra-wave LDS RAW only (wave w owns rows [32w,32w+32)) ----
    lsum += __shfl_xor(lsum, 32);
    if (hi == 0) lpart[(size_t)bid * 128 + w * 32 + l31] = lsum;
    {
        _Float16* sO = (_Float16*)&sK[0][0];           // [128][72] halves (stride 144 B)
        const int q = w * 32 + l31;
        #pragma unroll
        for (int u = 0; u < 4; ++u) {
            half4 v0, v1;
            v0[0] = (_Float16)acco0[4 * u];     v0[1] = (_Float16)acco0[4 * u + 1];
            v0[2] = (_Float16)acco0[4 * u + 2]; v0[3] = (_Float16)acco0[4 * u + 3];
            v1[0] = (_Float16)acco1[4 * u];     v1[1] = (_Float16)acco1[4 * u + 1];
            v1[2] = (_Float16)acco1[4 * u + 2]; v1[3] = (_Float16)acco1[4 * u + 3];
            *(half4*)&sO[q * 72 + u * 8 + 4 * hi]      = v0;   // dh = 8u + 4hi + 0..3
            *(half4*)&sO[q * 72 + 32 + u * 8 + 4 * hi] = v1;
        }
        const int qd = tid >> 1, hf = tid & 1;
        _Float16* dst = Opart + ((size_t)bid << 13) + qd * 64 + hf * 32;
        const _Float16* srcp = sO + qd * 72 + hf * 32;
        #pragma unroll
        for (int k = 0; k < 4; ++k)
            *(half8*)(dst + k * 8) = *(const half8*)(srcp + k * 8);
    }
}

extern "C" void kernel_launch(void* const* d_in, const int* in_sizes, int n_in,
                              void* d_out, int out_size, void* d_ws, size_t ws_size,
                              hipStream_t stream) {
    (void)in_sizes; (void)n_in; (void)out_size; (void)ws_size;
    const float* x      = (const float*)d_in[0];
    const float* Wq     = (const float*)d_in[1];
    const float* Wk     = (const float*)d_in[2];
    const float* Wv     = (const float*)d_in[3];
    const float* Wb     = (const float*)d_in[4];
    const float* mixing = (const float*)d_in[5];
    const float* Wd     = (const float*)d_in[6];
    const float* bd     = (const float*)d_in[7];
    float* out = (float*)d_out;

    char* ws = (char*)d_ws;
    const size_t MiB = 1048576;
    unsigned short* xb     = (unsigned short*)(ws);                  // [0,4) MiB
    unsigned short* qb     = (unsigned short*)(ws + 4 * MiB);        // [4,8) bf16 q row-major
    unsigned char*  kpack8 = (unsigned char*)(ws + 8 * MiB);         // [8,10) fp8 K A-frags (x32, K=64 layout)
    unsigned short* vfrag  = (unsigned short*)(ws + 10 * MiB);       // [10,14)
    unsigned short* Wqb    = (unsigned short*)(ws + 18 * MiB);
    unsigned short* Wkb    = (unsigned short*)(ws + 18 * MiB + 512 * 1024);
    unsigned short* Wvb    = (unsigned short*)(ws + 19 * MiB);
    unsigned short* Wdb    = (unsigned short*)(ws + 19 * MiB + 512 * 1024);
    float* cbuf            = (float*)(ws + 20 * MiB);                // 128 KB (f32 frag-major)
    float* lpart           = (float*)(ws + 20 * MiB + 256 * 1024);   // 256 KB
    _Float16* Opart        = (_Float16*)(ws + 21 * MiB);             // [21,29) 8 MB, q-major

    cvt_cb<<<4096, 256, 0, stream>>>(x, Wq, Wk, Wv, Wd, Wb, xb, Wqb, Wkb, Wvb, Wdb, cbuf);
    gemm_qkv<<<dim3(32, 4, 3), 256, 0, stream>>>(xb, Wqb, Wkb, Wvb, qb, kpack8, vfrag);
    flash_attn<<<512, 256, 0, stream>>>(qb, kpack8, vfrag, cbuf, mixing, Opart, lpart);
    gemm_out<<<dim3(32, 4), 256, 0, stream>>>(Opart, lpart, Wdb, bd, out);
}